// Round 5
// baseline (300.723 us; speedup 1.0000x reference)
//
#include <hip/hip_runtime.h>
#include <stdint.h>

#define M_DIM 8192
#define N_DIM 4096
#define K_DIM 4096
#define NT (K_DIM / 128)  // 32 k-tiles of 128 fp8 bytes

typedef float f32x4 __attribute__((ext_vector_type(4)));
typedef int v4i __attribute__((ext_vector_type(4)));
typedef int v8i __attribute__((ext_vector_type(8)));
typedef uint32_t u32;

// ---------- helpers ----------

__device__ __forceinline__ void gload_lds16(const void* g, void* l) {
  __builtin_amdgcn_global_load_lds(
      (__attribute__((address_space(1))) void*)(g),
      (__attribute__((address_space(3))) void*)(l), 16, 0, 0);
}

__device__ __forceinline__ float clipdiv(float v, float s) {
  v = v / s;
  return fminf(fmaxf(v, -448.f), 448.f);
}

__device__ __forceinline__ u32 pack4_fp8(float a, float b, float c, float d) {
  int w = __builtin_amdgcn_cvt_pk_fp8_f32(a, b, 0, false);
  w = __builtin_amdgcn_cvt_pk_fp8_f32(c, d, w, true);
  return (u32)w;
}

__device__ __forceinline__ v8i rd8(const void* lo, const void* hi) {
  v4i l = *(const v4i*)lo;
  v4i h = *(const v4i*)hi;
  return __builtin_shufflevector(l, h, 0, 1, 2, 3, 4, 5, 6, 7);
}

__device__ __forceinline__ f32x4 mfma8(v8i a, v8i b, f32x4 c) {
  return __builtin_amdgcn_mfma_scale_f32_16x16x128_f8f6f4(
      a, b, c, 0, 0, 0, 0x7f7f7f7f, 0, 0x7f7f7f7f);
}

// ---------- quantize A (row-major M x K, f32 -> e4m3fn) ----------

__global__ __launch_bounds__(256) void quant_a(const float* __restrict__ x,
                                               u32* __restrict__ q,
                                               const float* __restrict__ scale,
                                               int nv4) {
  int base = blockIdx.x * 1024 + threadIdx.x;
  float s = scale[0];
#pragma unroll
  for (int r = 0; r < 4; ++r) {
    int idx = base + r * 256;
    if (idx < nv4) {
      float4 v = ((const float4*)x)[idx];
      q[idx] = pack4_fp8(clipdiv(v.x, s), clipdiv(v.y, s),
                         clipdiv(v.z, s), clipdiv(v.w, s));
    }
  }
}

// ---------- quantize + transpose B (K x N f32 -> N x K fp8) ----------

__global__ __launch_bounds__(256) void quant_b_t(const float* __restrict__ B,
                                                 uint8_t* __restrict__ qT,
                                                 const float* __restrict__ scale) {
  __shared__ __align__(16) uint8_t lt[64 * 80];
  int tid = threadIdx.x;
  int kt = blockIdx.x * 64;
  int nt = blockIdx.y * 64;
  float s = scale[0];

  int kl = tid >> 4;
  int n4 = (tid & 15) * 4;
#pragma unroll
  for (int rep = 0; rep < 4; ++rep) {
    int k = kl + rep * 16;
    float4 v = *(const float4*)&B[(long)(kt + k) * N_DIM + nt + n4];
    u32 w = pack4_fp8(clipdiv(v.x, s), clipdiv(v.y, s),
                      clipdiv(v.z, s), clipdiv(v.w, s));
    lt[(n4 + 0) * 80 + k] = (uint8_t)(w & 0xff);
    lt[(n4 + 1) * 80 + k] = (uint8_t)((w >> 8) & 0xff);
    lt[(n4 + 2) * 80 + k] = (uint8_t)((w >> 16) & 0xff);
    lt[(n4 + 3) * 80 + k] = (uint8_t)(w >> 24);
  }
  __syncthreads();
  int n = tid >> 2, ch = tid & 3;
  uint4 o = *(const uint4*)&lt[n * 80 + ch * 16];
  *(uint4*)&qT[(long)(nt + n) * K_DIM + kt + ch * 16] = o;
}

// ---------- 256x256 8-phase MX-fp8 GEMM, B-resident wave tile 128x64 ----------
// 8 waves: wr=wid>>2 selects 128-row half of A, wc=wid&3 selects 64-col strip.
// Per K-tile (4 phases): P1 reads all B-frags (8 rd) + A-pair m01 (4 rd);
// P2..P4 read A-pairs only (4 rd) — B held in registers. 24 ds_read_b128 per
// wave per K-tile (the minimum), vs 48 in the quadrant scheme.
// Stage stream (1 half-tile/phase; every target slot's last reader is in a
// prior barrier-separated phase — B slots last read P1/P5, A slots P4/P8):
//   P1: Ah0(T+1)->b1  P2: Ah1(T+1)->b1  P3: Bh0(T+2)->b0  P4: Bh1(T+2)->b0
//   P5: Ah0(T+2)->b0  P6: Ah1(T+2)->b0  P7: Bh0(T+3)->b1  P8: Bh1(T+3)->b1
// vmcnt(4) at P4 end FIFO-drains tile T+1; at P8 end drains tile T+2.

__device__ __forceinline__ void stg(uint8_t* lds, const uint8_t* pA0,
                                    const uint8_t* pA1, const uint8_t* pB0,
                                    const uint8_t* pB1, int ld0, int ld1,
                                    int mat, int h, int t, int buf) {
  long ko = (long)((t & (NT - 1)) * 128) + (long)h * (128L * (long)K_DIM);
  const uint8_t* s0 = (mat ? pB0 : pA0) + ko;
  const uint8_t* s1 = (mat ? pB1 : pA1) + ko;
  uint8_t* d0 = lds + mat * 65536 + buf * 32768 + h * 16384 + ld0;
  uint8_t* d1 = lds + mat * 65536 + buf * 32768 + h * 16384 + ld1;
  gload_lds16(s0, d0);
  gload_lds16(s1, d1);
}

template <int BUF, int SEL>
__device__ __forceinline__ void ktile(uint8_t* lds, const int (&offA)[8][2],
                                      const int (&offB)[4][2], f32x4 (&acc)[8][4],
                                      int T, const uint8_t* pA0, const uint8_t* pA1,
                                      const uint8_t* pB0, const uint8_t* pB1,
                                      int ld0, int ld1, int abase, int bbase) {
  // stage maps: SEL=0 (first K-tile of pair), SEL=1 (second)
  constexpr int SM_[2][4] = {{0, 0, 1, 1}, {0, 0, 1, 1}};
  constexpr int SH_[2][4] = {{0, 1, 0, 1}, {0, 1, 0, 1}};
  constexpr int DT_[2][4] = {{1, 1, 2, 2}, {2, 2, 3, 3}};
  constexpr int SB_[2][4] = {{1, 1, 0, 0}, {0, 0, 1, 1}};

  const uint8_t* Ab = lds + BUF * 32768 + abase;
  const uint8_t* Bb = lds + 65536 + BUF * 32768 + bbase;

  v8i b[4];
#pragma unroll
  for (int nj = 0; nj < 4; ++nj) b[nj] = rd8(Bb + offB[nj][0], Bb + offB[nj][1]);

#pragma unroll
  for (int p = 0; p < 4; ++p) {
    v8i a0 = rd8(Ab + offA[2 * p][0], Ab + offA[2 * p][1]);
    v8i a1 = rd8(Ab + offA[2 * p + 1][0], Ab + offA[2 * p + 1][1]);
    stg(lds, pA0, pA1, pB0, pB1, ld0, ld1, SM_[SEL][p], SH_[SEL][p],
        T + DT_[SEL][p], SB_[SEL][p]);
    __builtin_amdgcn_s_barrier();
    asm volatile("s_waitcnt lgkmcnt(0)" ::: "memory");
    __builtin_amdgcn_sched_barrier(0);
    __builtin_amdgcn_s_setprio(1);
#pragma unroll
    for (int nj = 0; nj < 4; ++nj) {
      acc[2 * p][nj] = mfma8(a0, b[nj], acc[2 * p][nj]);
      acc[2 * p + 1][nj] = mfma8(a1, b[nj], acc[2 * p + 1][nj]);
    }
    __builtin_amdgcn_s_setprio(0);
    if (p == 3) asm volatile("s_waitcnt vmcnt(4)" ::: "memory");
    __builtin_amdgcn_s_barrier();
  }
}

__global__ __launch_bounds__(512, 2) void gemm_mx8(const uint8_t* __restrict__ Aq,
                                                   const uint8_t* __restrict__ BqT,
                                                   float* __restrict__ C,
                                                   const float* __restrict__ sA,
                                                   const float* __restrict__ sB) {
  __shared__ __align__(16) uint8_t lds[131072];

  const int tid = threadIdx.x;
  const int lane = tid & 63;
  const int wid = tid >> 6;
  const int wr = wid >> 2;  // 0..1: 128-row half of A
  const int wc = wid & 3;   // 0..3: 64-col strip of B
  const int r16 = lane & 15;
  const int hi = lane >> 4;

  // XCD-aware swizzle: 512 wgs, 64 per XCD chunk (bijective, 512%8==0)
  int bid = blockIdx.x;
  int wg = (bid & 7) * 64 + (bid >> 3);
  const long bm = (long)(wg >> 4) * 256;  // 32 M-tiles
  const long bn = (long)(wg & 15) * 256;  // 16 N-tiles

  // scales: materialize BEFORE staging so their loads never sit in the vmem
  // queue during the counted vmcnt waits.
  float s = sA[0] * sB[0];
  asm volatile("" ::"v"(s));

  // staging invariants: 2 granules of 16B per thread per half-tile
  const int gid0 = tid, gid1 = tid + 512;
  const int row0 = gid0 >> 3, row1 = gid1 >> 3;  // row within 128-row half
  const int sc0 = ((gid0 & 7) ^ (row0 & 7)) << 4;
  const int sc1 = ((gid1 & 7) ^ (row1 & 7)) << 4;
  const uint8_t* pA0 = Aq + (bm + row0) * (long)K_DIM + sc0;
  const uint8_t* pA1 = Aq + (bm + row1) * (long)K_DIM + sc1;
  const uint8_t* pB0 = BqT + (bn + row0) * (long)K_DIM + sc0;
  const uint8_t* pB1 = BqT + (bn + row1) * (long)K_DIM + sc1;
  const int ld0 = gid0 * 16, ld1 = gid1 * 16;
  const int abase = wr * 16384;
  const int bbase = (wc >> 1) * 16384;

  // fragment read offsets (loop-invariant, swizzled). rows are within-half.
  int offA[8][2], offB[4][2];
#pragma unroll
  for (int mi = 0; mi < 8; ++mi) {
    int ra = mi * 16 + r16;  // 0..127
#pragma unroll
    for (int g = 0; g < 2; ++g) {
      int lg = 2 * hi + g;
      offA[mi][g] = ra * 128 + ((lg ^ (ra & 7)) << 4);
    }
  }
#pragma unroll
  for (int nj = 0; nj < 4; ++nj) {
    int rb = (wc & 1) * 64 + nj * 16 + r16;  // 0..127
#pragma unroll
    for (int g = 0; g < 2; ++g) {
      int lg = 2 * hi + g;
      offB[nj][g] = rb * 128 + ((lg ^ (rb & 7)) << 4);
    }
  }

  f32x4 acc[8][4] = {};

  // ---- prologue: tile0 (4 halves) + Bh0(1), Bh1(1); drain tile0 ----
  stg(lds, pA0, pA1, pB0, pB1, ld0, ld1, 0, 0, 0, 0);  // Ah0(0)->b0
  stg(lds, pA0, pA1, pB0, pB1, ld0, ld1, 0, 1, 0, 0);  // Ah1(0)->b0
  stg(lds, pA0, pA1, pB0, pB1, ld0, ld1, 1, 0, 0, 0);  // Bh0(0)->b0
  stg(lds, pA0, pA1, pB0, pB1, ld0, ld1, 1, 1, 0, 0);  // Bh1(0)->b0
  stg(lds, pA0, pA1, pB0, pB1, ld0, ld1, 1, 0, 1, 1);  // Bh0(1)->b1
  stg(lds, pA0, pA1, pB0, pB1, ld0, ld1, 1, 1, 1, 1);  // Bh1(1)->b1
  asm volatile("s_waitcnt vmcnt(4)" ::: "memory");     // tile0 complete
  __builtin_amdgcn_s_barrier();

  // ---- main loop: 2 K-tiles (8 phases) per iteration ----
  for (int i = 0; i < NT / 2; ++i) {
    int T = 2 * i;
    ktile<0, 0>(lds, offA, offB, acc, T, pA0, pA1, pB0, pB1, ld0, ld1, abase, bbase);
    ktile<1, 1>(lds, offA, offB, acc, T, pA0, pA1, pB0, pB1, ld0, ld1, abase, bbase);
  }

  // ---- epilogue: C-write ----
#pragma unroll
  for (int mi = 0; mi < 8; ++mi)
#pragma unroll
    for (int nj = 0; nj < 4; ++nj) {
      long row = bm + wr * 128 + mi * 16 + hi * 4;
      long col = bn + wc * 64 + nj * 16 + r16;
      float* cp = C + row * N_DIM + col;
      f32x4 v = acc[mi][nj];
#pragma unroll
      for (int e = 0; e < 4; ++e) cp[(long)e * N_DIM] = v[e] * s;
    }
}

// ---------- launcher ----------

extern "C" void kernel_launch(void* const* d_in, const int* in_sizes, int n_in,
                              void* d_out, int out_size, void* d_ws, size_t ws_size,
                              hipStream_t stream) {
  const float* A = (const float*)d_in[0];   // (8192, 4096)
  const float* B = (const float*)d_in[1];   // (4096, 4096)
  const float* sA = (const float*)d_in[2];  // input_scale
  const float* sB = (const float*)d_in[4];  // kernel_scale
  float* out = (float*)d_out;

  uint8_t* Aq = (uint8_t*)d_ws;               // M*K fp8
  uint8_t* BqT = Aq + (size_t)M_DIM * K_DIM;  // N*K fp8 (transposed)

  int nv4_a = M_DIM * K_DIM / 4;
  quant_a<<<nv4_a / 1024, 256, 0, stream>>>(A, (u32*)Aq, sA, nv4_a);
  quant_b_t<<<dim3(K_DIM / 64, N_DIM / 64), 256, 0, stream>>>(B, BqT, sB);
  gemm_mx8<<<dim3((M_DIM / 256) * (N_DIM / 256)), 512, 0, stream>>>(Aq, BqT, out, sA, sB);
}

// Round 6
// 202.361 us; speedup vs baseline: 1.4861x; 1.4861x over previous
//
#include <hip/hip_runtime.h>
#include <stdint.h>

#define M_DIM 8192
#define N_DIM 4096
#define K_DIM 4096
#define NT (K_DIM / 128)  // 32 k-tiles of 128 fp8 bytes

typedef float f32x4 __attribute__((ext_vector_type(4)));
typedef int v4i __attribute__((ext_vector_type(4)));
typedef int v8i __attribute__((ext_vector_type(8)));
typedef uint32_t u32;

// ---------- helpers ----------

__device__ __forceinline__ void gload_lds16(const void* g, void* l) {
  __builtin_amdgcn_global_load_lds(
      (__attribute__((address_space(1))) void*)(g),
      (__attribute__((address_space(3))) void*)(l), 16, 0, 0);
}

__device__ __forceinline__ float clipdiv(float v, float s) {
  v = v / s;
  return fminf(fmaxf(v, -448.f), 448.f);
}

__device__ __forceinline__ u32 pack4_fp8(float a, float b, float c, float d) {
  int w = __builtin_amdgcn_cvt_pk_fp8_f32(a, b, 0, false);
  w = __builtin_amdgcn_cvt_pk_fp8_f32(c, d, w, true);
  return (u32)w;
}

__device__ __forceinline__ v8i rd8(const void* lo, const void* hi) {
  v4i l = *(const v4i*)lo;
  v4i h = *(const v4i*)hi;
  return __builtin_shufflevector(l, h, 0, 1, 2, 3, 4, 5, 6, 7);
}

__device__ __forceinline__ f32x4 mfma8(v8i a, v8i b, f32x4 c) {
  return __builtin_amdgcn_mfma_scale_f32_16x16x128_f8f6f4(
      a, b, c, 0, 0, 0, 0x7f7f7f7f, 0, 0x7f7f7f7f);
}

// ---------- quantize A (row-major M x K, f32 -> e4m3fn) ----------

__global__ __launch_bounds__(256) void quant_a(const float* __restrict__ x,
                                               u32* __restrict__ q,
                                               const float* __restrict__ scale,
                                               int nv4) {
  int base = blockIdx.x * 1024 + threadIdx.x;
  float s = scale[0];
#pragma unroll
  for (int r = 0; r < 4; ++r) {
    int idx = base + r * 256;
    if (idx < nv4) {
      float4 v = ((const float4*)x)[idx];
      q[idx] = pack4_fp8(clipdiv(v.x, s), clipdiv(v.y, s),
                         clipdiv(v.z, s), clipdiv(v.w, s));
    }
  }
}

// ---------- quantize + transpose B (K x N f32 -> N x K fp8) ----------

__global__ __launch_bounds__(256) void quant_b_t(const float* __restrict__ B,
                                                 uint8_t* __restrict__ qT,
                                                 const float* __restrict__ scale) {
  __shared__ __align__(16) uint8_t lt[64 * 80];
  int tid = threadIdx.x;
  int kt = blockIdx.x * 64;
  int nt = blockIdx.y * 64;
  float s = scale[0];

  int kl = tid >> 4;
  int n4 = (tid & 15) * 4;
#pragma unroll
  for (int rep = 0; rep < 4; ++rep) {
    int k = kl + rep * 16;
    float4 v = *(const float4*)&B[(long)(kt + k) * N_DIM + nt + n4];
    u32 w = pack4_fp8(clipdiv(v.x, s), clipdiv(v.y, s),
                      clipdiv(v.z, s), clipdiv(v.w, s));
    lt[(n4 + 0) * 80 + k] = (uint8_t)(w & 0xff);
    lt[(n4 + 1) * 80 + k] = (uint8_t)((w >> 8) & 0xff);
    lt[(n4 + 2) * 80 + k] = (uint8_t)((w >> 16) & 0xff);
    lt[(n4 + 3) * 80 + k] = (uint8_t)(w >> 24);
  }
  __syncthreads();
  int n = tid >> 2, ch = tid & 3;
  uint4 o = *(const uint4*)&lt[n * 80 + ch * 16];
  *(uint4*)&qT[(long)(nt + n) * K_DIM + kt + ch * 16] = o;
}

// ---------- MX-fp8 GEMM, 128x128 tile, double-buffered 2-phase ----------
// Exactly the round-2 winner (1696 TF) + T3-minimum pipeline:
//   prologue: STAGE(buf0, 0); vmcnt(0); barrier
//   loop:     STAGE(buf^1, t+1) issued FIRST; ds_read+MFMA on buf
//             (compiler-managed lgkmcnt); vmcnt(0); barrier
// so the stage's HBM/L2 latency hides under the tile's reads+MFMA instead of
// being drained immediately after issue. LDS 64 KiB -> 2 wgs/CU.
// Race audit: WAR barrier-ordered (reads of a buffer drain before each wave's
// MFMA; the opposite-buffer stage is issued after the barrier), RAW by the
// bottom vmcnt(0). Same granule swizzle as round 2 (pre-swizzled global
// source + swizzled ds_read, rule #21).

template <int BUF>
__device__ __forceinline__ void compute_tile(const uint8_t* lds,
                                             const int (&offA)[4][2],
                                             const int (&offB)[4][2],
                                             f32x4 (&acc)[4][4]) {
  const uint8_t* Ab = lds + BUF * 32768;
  const uint8_t* Bb = lds + BUF * 32768 + 16384;
  v8i a[4], b[4];
#pragma unroll
  for (int i = 0; i < 4; ++i) a[i] = rd8(Ab + offA[i][0], Ab + offA[i][1]);
#pragma unroll
  for (int j = 0; j < 4; ++j) b[j] = rd8(Bb + offB[j][0], Bb + offB[j][1]);
#pragma unroll
  for (int i = 0; i < 4; ++i)
#pragma unroll
    for (int j = 0; j < 4; ++j) acc[i][j] = mfma8(a[i], b[j], acc[i][j]);
}

template <int BUF>
__device__ __forceinline__ void stage_tile(const uint8_t* const (&gA)[4],
                                           const uint8_t* const (&gB)[4],
                                           uint8_t* lds, const int (&ldo)[4],
                                           long ko) {
#pragma unroll
  for (int r = 0; r < 4; ++r)
    gload_lds16(gA[r] + ko, lds + BUF * 32768 + ldo[r]);
#pragma unroll
  for (int r = 0; r < 4; ++r)
    gload_lds16(gB[r] + ko, lds + BUF * 32768 + 16384 + ldo[r]);
}

__global__ __launch_bounds__(256) void gemm_mx(const uint8_t* __restrict__ Aq,
                                               const uint8_t* __restrict__ BqT,
                                               float* __restrict__ C,
                                               const float* __restrict__ sA,
                                               const float* __restrict__ sB) {
  __shared__ __align__(16) uint8_t lds[65536];  // 2 bufs x (A 16K + B 16K)

  const int tid = threadIdx.x;
  const int lane = tid & 63;
  const int w = tid >> 6;
  const int wr = w >> 1, wc = w & 1;
  const long bm = (long)blockIdx.y * 128;
  const long bn = (long)blockIdx.x * 128;

  // scales: materialize before staging so their loads never sit in the vmem
  // queue during the counted waits.
  float s = sA[0] * sB[0];
  asm volatile("" ::"v"(s));

  // --- staging: 1024 granules per matrix, 4 per thread, pre-swizzled src ---
  const uint8_t* gA[4];
  const uint8_t* gB[4];
  int ldo[4];
#pragma unroll
  for (int r = 0; r < 4; ++r) {
    int gid = tid + 256 * r;
    int row = gid >> 3, gc = gid & 7;
    int sc = (gc ^ (row & 7)) << 4;  // pre-swizzled source granule
    gA[r] = Aq + (bm + row) * (long)K_DIM + sc;
    gB[r] = BqT + (bn + row) * (long)K_DIM + sc;
    ldo[r] = gid * 16;  // linear LDS dest
  }

  // --- fragment read offsets (loop-invariant, swizzled) ---
  const int r16 = lane & 15;
  const int hi = lane >> 4;
  int offA[4][2], offB[4][2];
#pragma unroll
  for (int i = 0; i < 4; ++i) {
    int ra = wr * 64 + i * 16 + r16;
    int rb = wc * 64 + i * 16 + r16;
#pragma unroll
    for (int g = 0; g < 2; ++g) {
      int lg = 2 * hi + g;
      offA[i][g] = ra * 128 + ((lg ^ (ra & 7)) << 4);
      offB[i][g] = rb * 128 + ((lg ^ (rb & 7)) << 4);
    }
  }

  f32x4 acc[4][4] = {};

  // ---- prologue ----
  stage_tile<0>(gA, gB, lds, ldo, 0);
  asm volatile("s_waitcnt vmcnt(0)" ::: "memory");
  __builtin_amdgcn_s_barrier();

  // ---- main loop: 2 K-tiles per iteration, static buffer indices ----
  for (int i = 0; i < NT / 2; ++i) {
    long ko1 = (long)((2 * i + 1) & (NT - 1)) * 128;
    stage_tile<1>(gA, gB, lds, ldo, ko1);     // issue first
    compute_tile<0>(lds, offA, offB, acc);    // reads + 16 MFMA
    asm volatile("s_waitcnt vmcnt(0)" ::: "memory");
    __builtin_amdgcn_s_barrier();

    long ko2 = (long)((2 * i + 2) & (NT - 1)) * 128;  // wraps harmlessly
    stage_tile<0>(gA, gB, lds, ldo, ko2);
    compute_tile<1>(lds, offA, offB, acc);
    asm volatile("s_waitcnt vmcnt(0)" ::: "memory");
    __builtin_amdgcn_s_barrier();
  }

  // ---- epilogue: C-write ----
#pragma unroll
  for (int i = 0; i < 4; ++i)
#pragma unroll
    for (int j = 0; j < 4; ++j) {
      long row = bm + wr * 64 + i * 16 + hi * 4;  // C/D: row=(lane>>4)*4+q
      long col = bn + wc * 64 + j * 16 + r16;     //      col=lane&15
      float* cp = C + row * N_DIM + col;
#pragma unroll
      for (int q = 0; q < 4; ++q) cp[(long)q * N_DIM] = acc[i][j][q] * s;
    }
}

// ---------- launcher ----------

extern "C" void kernel_launch(void* const* d_in, const int* in_sizes, int n_in,
                              void* d_out, int out_size, void* d_ws, size_t ws_size,
                              hipStream_t stream) {
  const float* A = (const float*)d_in[0];   // (8192, 4096)
  const float* B = (const float*)d_in[1];   // (4096, 4096)
  const float* sA = (const float*)d_in[2];  // input_scale
  const float* sB = (const float*)d_in[4];  // kernel_scale
  float* out = (float*)d_out;

  uint8_t* Aq = (uint8_t*)d_ws;               // M*K fp8
  uint8_t* BqT = Aq + (size_t)M_DIM * K_DIM;  // N*K fp8 (transposed)

  int nv4_a = M_DIM * K_DIM / 4;
  quant_a<<<nv4_a / 1024, 256, 0, stream>>>(A, (u32*)Aq, sA, nv4_a);
  quant_b_t<<<dim3(K_DIM / 64, N_DIM / 64), 256, 0, stream>>>(B, BqT, sB);
  gemm_mx<<<dim3(N_DIM / 128, M_DIM / 128), 256, 0, stream>>>(Aq, BqT, out, sA, sB);
}

// Round 7
// 188.944 us; speedup vs baseline: 1.5916x; 1.0710x over previous
//
#include <hip/hip_runtime.h>
#include <stdint.h>

#define M_DIM 8192
#define N_DIM 4096
#define K_DIM 4096
#define NT (K_DIM / 128)  // 32 k-tiles of 128 fp8 bytes

typedef float f32x4 __attribute__((ext_vector_type(4)));
typedef int v4i __attribute__((ext_vector_type(4)));
typedef int v8i __attribute__((ext_vector_type(8)));
typedef uint32_t u32;

// ---------- helpers ----------

__device__ __forceinline__ void gload_lds16(const void* g, void* l) {
  __builtin_amdgcn_global_load_lds(
      (__attribute__((address_space(1))) void*)(g),
      (__attribute__((address_space(3))) void*)(l), 16, 0, 0);
}

__device__ __forceinline__ float clipdiv(float v, float s) {
  v = v / s;
  return fminf(fmaxf(v, -448.f), 448.f);
}

__device__ __forceinline__ u32 pack4_fp8(float a, float b, float c, float d) {
  int w = __builtin_amdgcn_cvt_pk_fp8_f32(a, b, 0, false);
  w = __builtin_amdgcn_cvt_pk_fp8_f32(c, d, w, true);
  return (u32)w;
}

__device__ __forceinline__ v8i rd8(const void* lo, const void* hi) {
  v4i l = *(const v4i*)lo;
  v4i h = *(const v4i*)hi;
  return __builtin_shufflevector(l, h, 0, 1, 2, 3, 4, 5, 6, 7);
}

__device__ __forceinline__ f32x4 mfma8(v8i a, v8i b, f32x4 c) {
  return __builtin_amdgcn_mfma_scale_f32_16x16x128_f8f6f4(
      a, b, c, 0, 0, 0, 0x7f7f7f7f, 0, 0x7f7f7f7f);
}

// ---------- quantize A (row-major M x K, f32 -> e4m3fn) ----------

__global__ __launch_bounds__(256) void quant_a(const float* __restrict__ x,
                                               u32* __restrict__ q,
                                               const float* __restrict__ scale,
                                               int nv4) {
  int base = blockIdx.x * 1024 + threadIdx.x;
  float s = scale[0];
#pragma unroll
  for (int r = 0; r < 4; ++r) {
    int idx = base + r * 256;
    if (idx < nv4) {
      float4 v = ((const float4*)x)[idx];
      q[idx] = pack4_fp8(clipdiv(v.x, s), clipdiv(v.y, s),
                         clipdiv(v.z, s), clipdiv(v.w, s));
    }
  }
}

// ---------- quantize + transpose B (K x N f32 -> N x K fp8), u32-packed ----
// Each thread owns a 4(k) x 4(n) micro-tile: 4 coalesced float4 loads,
// packs 4 u32 (one per n, 4 ascending k-bytes each), writes them to LDS
// rows padded to 17 dwords (write banks: (4nq+kq) spans 0..63 -> 2-way max;
// read banks: 17n+4ch -> 2-way max; both free per m136).

__global__ __launch_bounds__(256) void quant_b_t(const float* __restrict__ B,
                                                 uint8_t* __restrict__ qT,
                                                 const float* __restrict__ scale) {
  __shared__ u32 lt[64 * 17];  // 64 n-rows x 16 dwords + 1 pad
  int tid = threadIdx.x;
  int kt = blockIdx.x * 64;
  int nt = blockIdx.y * 64;
  float s = scale[0];

  int kq = tid >> 4;  // 0..15 -> k0 = 4*kq
  int nq = tid & 15;  // 0..15 -> n0 = 4*nq
  int k0 = kq * 4, n0 = nq * 4;
  const float* src = B + (long)(kt + k0) * N_DIM + nt + n0;
  float4 v0 = *(const float4*)(src);
  float4 v1 = *(const float4*)(src + N_DIM);
  float4 v2 = *(const float4*)(src + 2 * N_DIM);
  float4 v3 = *(const float4*)(src + 3 * N_DIM);

  lt[(n0 + 0) * 17 + kq] = pack4_fp8(clipdiv(v0.x, s), clipdiv(v1.x, s),
                                     clipdiv(v2.x, s), clipdiv(v3.x, s));
  lt[(n0 + 1) * 17 + kq] = pack4_fp8(clipdiv(v0.y, s), clipdiv(v1.y, s),
                                     clipdiv(v2.y, s), clipdiv(v3.y, s));
  lt[(n0 + 2) * 17 + kq] = pack4_fp8(clipdiv(v0.z, s), clipdiv(v1.z, s),
                                     clipdiv(v2.z, s), clipdiv(v3.z, s));
  lt[(n0 + 3) * 17 + kq] = pack4_fp8(clipdiv(v0.w, s), clipdiv(v1.w, s),
                                     clipdiv(v2.w, s), clipdiv(v3.w, s));
  __syncthreads();

  int n = tid >> 2, ch = tid & 3;
  uint4 o;
  o.x = lt[n * 17 + ch * 4 + 0];
  o.y = lt[n * 17 + ch * 4 + 1];
  o.z = lt[n * 17 + ch * 4 + 2];
  o.w = lt[n * 17 + ch * 4 + 3];
  *(uint4*)&qT[(long)(nt + n) * K_DIM + kt + ch * 16] = o;
}

// ---------- 256x256 MX-fp8 GEMM, coarse double-buffered 2-phase ----------
// Round-6's proven schedule at 2x the tile: 8 waves (2M x 4N), wave tile
// 128x64 -> per wave per K-tile exactly 24 ds_read_b128 (the minimum:
// (128+64)*128B / 1KB) and 32 MFMA. B-frags register-resident; A read in two
// 4-frag chunks to bound VGPR. Per K-tile: stage(buf^1, t+1) issued FIRST,
// compute(buf), single vmcnt(0) + s_barrier.
// LDS 128 KiB: A [0,64K) = 2 bufs x 32K, B [64K,128K) = 2 bufs x 32K.
// Same granule swizzle as rounds 2/6 (pre-swizzled global source + swizzled
// ds_read, rule #21). WAR: each wave's reads retire before its MFMAs
// (compiler lgkmcnt) hence before the barrier; opposite-buffer stage lands
// after it. RAW: vmcnt(0) before the barrier.

template <int BUF>
__device__ __forceinline__ void stage_tile(const uint8_t* const (&gA)[4],
                                           const uint8_t* const (&gB)[4],
                                           uint8_t* lds, const int (&ldo)[4],
                                           long ko) {
#pragma unroll
  for (int r = 0; r < 4; ++r)
    gload_lds16(gA[r] + ko, lds + BUF * 32768 + ldo[r]);
#pragma unroll
  for (int r = 0; r < 4; ++r)
    gload_lds16(gB[r] + ko, lds + 65536 + BUF * 32768 + ldo[r]);
}

template <int BUF>
__device__ __forceinline__ void compute_tile(const uint8_t* lds,
                                             const int (&offA)[8][2],
                                             const int (&offB)[4][2],
                                             f32x4 (&acc)[8][4]) {
  const uint8_t* Ab = lds + BUF * 32768;
  const uint8_t* Bb = lds + 65536 + BUF * 32768;
  v8i b[4];
#pragma unroll
  for (int j = 0; j < 4; ++j) b[j] = rd8(Bb + offB[j][0], Bb + offB[j][1]);
#pragma unroll
  for (int h = 0; h < 2; ++h) {
    v8i a[4];
#pragma unroll
    for (int i = 0; i < 4; ++i)
      a[i] = rd8(Ab + offA[h * 4 + i][0], Ab + offA[h * 4 + i][1]);
#pragma unroll
    for (int i = 0; i < 4; ++i)
#pragma unroll
      for (int j = 0; j < 4; ++j)
        acc[h * 4 + i][j] = mfma8(a[i], b[j], acc[h * 4 + i][j]);
  }
}

__global__ __launch_bounds__(512, 2) void gemm_mx(const uint8_t* __restrict__ Aq,
                                                  const uint8_t* __restrict__ BqT,
                                                  float* __restrict__ C,
                                                  const float* __restrict__ sA,
                                                  const float* __restrict__ sB) {
  __shared__ __align__(16) uint8_t lds[131072];

  const int tid = threadIdx.x;
  const int lane = tid & 63;
  const int wid = tid >> 6;
  const int wr = wid >> 2;  // 0..1: 128-row strip of A
  const int wc = wid & 3;   // 0..3: 64-col strip of B
  const int r16 = lane & 15;
  const int hi = lane >> 4;

  // XCD-aware swizzle: 512 wgs, 64 per XCD chunk (bijective, 512%8==0)
  int bid = blockIdx.x;
  int wg = (bid & 7) * 64 + (bid >> 3);
  const long bm = (long)(wg >> 4) * 256;  // 32 M-tiles
  const long bn = (long)(wg & 15) * 256;  // 16 N-tiles

  // scales: materialize before staging so their loads never sit in the vmem
  // queue during the counted waits.
  float s = sA[0] * sB[0];
  asm volatile("" ::"v"(s));

  // --- staging: 2048 granules per matrix, 4 per thread, pre-swizzled src ---
  const uint8_t* gA[4];
  const uint8_t* gB[4];
  int ldo[4];
#pragma unroll
  for (int r = 0; r < 4; ++r) {
    int gid = tid + 512 * r;
    int row = gid >> 3, gc = gid & 7;
    int sc = (gc ^ (row & 7)) << 4;  // pre-swizzled source granule
    gA[r] = Aq + (bm + row) * (long)K_DIM + sc;
    gB[r] = BqT + (bn + row) * (long)K_DIM + sc;
    ldo[r] = gid * 16;  // linear LDS dest
  }

  // --- fragment read offsets (loop-invariant, swizzled) ---
  int offA[8][2], offB[4][2];
#pragma unroll
  for (int mi = 0; mi < 8; ++mi) {
    int ra = wr * 128 + mi * 16 + r16;  // 0..255
#pragma unroll
    for (int g = 0; g < 2; ++g) {
      int lg = 2 * hi + g;
      offA[mi][g] = ra * 128 + ((lg ^ (ra & 7)) << 4);
    }
  }
#pragma unroll
  for (int nj = 0; nj < 4; ++nj) {
    int rb = wc * 64 + nj * 16 + r16;  // 0..255
#pragma unroll
    for (int g = 0; g < 2; ++g) {
      int lg = 2 * hi + g;
      offB[nj][g] = rb * 128 + ((lg ^ (rb & 7)) << 4);
    }
  }

  f32x4 acc[8][4] = {};

  // ---- prologue ----
  stage_tile<0>(gA, gB, lds, ldo, 0);
  asm volatile("s_waitcnt vmcnt(0)" ::: "memory");
  __builtin_amdgcn_s_barrier();

  // ---- main loop: 2 K-tiles per iteration, static buffer indices ----
  for (int i = 0; i < NT / 2; ++i) {
    long ko1 = (long)((2 * i + 1) & (NT - 1)) * 128;
    stage_tile<1>(gA, gB, lds, ldo, ko1);   // issue first
    compute_tile<0>(lds, offA, offB, acc);  // 24 reads + 32 MFMA per wave
    asm volatile("s_waitcnt vmcnt(0)" ::: "memory");
    __builtin_amdgcn_s_barrier();

    long ko2 = (long)((2 * i + 2) & (NT - 1)) * 128;  // wraps harmlessly
    stage_tile<0>(gA, gB, lds, ldo, ko2);
    compute_tile<1>(lds, offA, offB, acc);
    asm volatile("s_waitcnt vmcnt(0)" ::: "memory");
    __builtin_amdgcn_s_barrier();
  }

  // ---- epilogue: C-write ----
  const float sc = s;
#pragma unroll
  for (int mi = 0; mi < 8; ++mi)
#pragma unroll
    for (int nj = 0; nj < 4; ++nj) {
      long row = bm + wr * 128 + mi * 16 + hi * 4;  // C/D: row=(lane>>4)*4+q
      long col = bn + wc * 64 + nj * 16 + r16;      //      col=lane&15
      float* cp = C + row * N_DIM + col;
      f32x4 v = acc[mi][nj];
#pragma unroll
      for (int q = 0; q < 4; ++q) cp[(long)q * N_DIM] = v[q] * sc;
    }
}

// ---------- launcher ----------

extern "C" void kernel_launch(void* const* d_in, const int* in_sizes, int n_in,
                              void* d_out, int out_size, void* d_ws, size_t ws_size,
                              hipStream_t stream) {
  const float* A = (const float*)d_in[0];   // (8192, 4096)
  const float* B = (const float*)d_in[1];   // (4096, 4096)
  const float* sA = (const float*)d_in[2];  // input_scale
  const float* sB = (const float*)d_in[4];  // kernel_scale
  float* out = (float*)d_out;

  uint8_t* Aq = (uint8_t*)d_ws;               // M*K fp8
  uint8_t* BqT = Aq + (size_t)M_DIM * K_DIM;  // N*K fp8 (transposed)

  int nv4_a = M_DIM * K_DIM / 4;
  quant_a<<<nv4_a / 1024, 256, 0, stream>>>(A, (u32*)Aq, sA, nv4_a);
  quant_b_t<<<dim3(K_DIM / 64, N_DIM / 64), 256, 0, stream>>>(B, BqT, sB);
  gemm_mx<<<dim3((M_DIM / 256) * (N_DIM / 256)), 512, 0, stream>>>(Aq, BqT, out, sA, sB);
}